// Round 11
// baseline (164.738 us; speedup 1.0000x reference)
//
#include <hip/hip_runtime.h>

#define NE 800000
#define NN 50000
#define MAXD 64
#define FILL_BLK (NE / 256)   // 3125 edge-MLP blocks (exact)
#define XC_BLK (NN / 8)       // 6250 repack blocks (exact)
#define PSTR 516              // LDS P row stride in f16 (pad 4 -> conflict-free)

typedef __attribute__((ext_vector_type(4))) unsigned short ushort4v;
typedef __attribute__((ext_vector_type(4))) _Float16 f16x4;
typedef __attribute__((ext_vector_type(4))) float f32x4;

static constexpr float ALPHA      = 0.08838834764831845f;   // 1/sqrt(128)
static constexpr float INV3       = 0.57735026918962576f;   // 1/sqrt(3)
static constexpr float INV_SQRT10 = 0.31622776601683794f;
static constexpr float SILU_NORM  = 1.679177f;
static constexpr float QSCALE     = ALPHA * 0.25f;          // fold 1/sqrt(16)

__device__ __forceinline__ unsigned short f2h_bits(float f) {
  _Float16 h = (_Float16)f;
  unsigned short b;
  __builtin_memcpy(&b, &h, 2);
  return b;
}
__device__ __forceinline__ float h2f_bits(unsigned int b) {
  unsigned short s = (unsigned short)b;
  _Float16 h;
  __builtin_memcpy(&h, &s, 2);
  return (float)h;
}
__device__ __forceinline__ unsigned int packh2(float lo, float hi) {
  return (unsigned int)f2h_bits(lo) | ((unsigned int)f2h_bits(hi) << 16);
}

// ---- fused: edge MLP -> ELL fill (blocks [0, FILL_BLK)) and
//      X f32 -> f16 repack (blocks [FILL_BLK, FILL_BLK+XC_BLK)).
__global__ __launch_bounds__(256) void k_combo(
    const float* __restrict__ X, unsigned short* __restrict__ Xp,
    const float* __restrict__ attr, const float* __restrict__ emb,
    const float* __restrict__ w1, const float* __restrict__ w2,
    const int* __restrict__ esrc, const int* __restrict__ edst,
    int* __restrict__ cur, uint4* __restrict__ ell) {
  __shared__ float lds[2816];  // 11.3 KB, shared by both paths
  if (blockIdx.x < FILL_BLK) {
    // ---- edge MLP + ELL fill; atomic issued EARLY, hidden under MLP ----
    int eb = blockIdx.x * 256;
    int e = eb + threadIdx.x;
    int dst = edst[e];
    int src = esrc[e];
    float4 a = *(const float4*)(attr + (size_t)e * 4);
    int slot = atomicAdd(&cur[dst], 1);

    const float* ebase = emb + (size_t)eb * 10;
#pragma unroll
    for (int j = 0; j < 10; j++)
      lds[j * 256 + threadIdx.x] = ebase[j * 256 + threadIdx.x];
    __syncthreads();
    const float* x = lds + threadIdx.x * 10;
    float r = 0.f;
#pragma unroll
    for (int j = 0; j < 64; j++) {
      float d = 0.f;
#pragma unroll
      for (int k = 0; k < 10; k++) d = fmaf(x[k], w1[k * 64 + j], d);
      d *= INV_SQRT10;
      float h = d * __builtin_amdgcn_rcpf(1.f + __expf(-d)) * SILU_NORM;
      r = fmaf(h, w2[j], r);
    }
    r *= 0.125f * QSCALE;  // fold 1/sqrt(64), alpha, 1/sqrt(16)
    if (slot < MAXD) {
      // single 16B scattered store per edge (one cache line touched)
      ell[(size_t)dst * MAXD + slot] =
          make_uint4((unsigned)src, packh2(r * a.x, r * a.y),
                     packh2(r * a.z, r * a.w), 0u);
    }
  } else {
    // ---- X -> Xp repack: 8 node rows staged via coalesced float4 loads ----
    int n0 = (blockIdx.x - FILL_BLK) * 8;
    const float4* Xs = (const float4*)(X + (size_t)n0 * 256);
    float4* L4 = (float4*)lds;
    L4[threadIdx.x] = Xs[threadIdx.x];
    L4[256 + threadIdx.x] = Xs[256 + threadIdx.x];
    __syncthreads();
    int o = threadIdx.x & 63;
    int nl = threadIdx.x >> 6;
#pragma unroll
    for (int ii = 0; ii < 2; ii++) {
      int n_l = nl + ii * 4;
      const float* row = lds + n_l * 256;
      ushort4v v;
      v[0] = f2h_bits(row[o]);
      v[1] = f2h_bits(row[64 + 3 * o]);
      v[2] = f2h_bits(row[64 + 3 * o + 1]);
      v[3] = f2h_bits(row[64 + 3 * o + 2]);
      *(ushort4v*)(Xp + (size_t)(n0 + n_l) * 256 + o * 4) = v;
    }
  }
}

// ---- raw-feature accumulate for one edge ----
__device__ __forceinline__ void eop(unsigned int q01, unsigned int q23,
                                    ushort4v y, float& u0, float& u1,
                                    float& v0, float& v1, float& v2, float& w0,
                                    float& w1, float& w2) {
  float q0 = h2f_bits(q01), q1 = h2f_bits(q01 >> 16);
  float q2 = h2f_bits(q23), q3 = h2f_bits(q23 >> 16);
  float x0 = h2f_bits(y[0]), xa = h2f_bits(y[1]);
  float xb = h2f_bits(y[2]), xc = h2f_bits(y[3]);
  u0 = fmaf(q0, x0, u0);
  u1 = fmaf(q1, xa, u1);
  u1 = fmaf(q2, xb, u1);
  u1 = fmaf(q3, xc, u1);
  v0 = fmaf(q1, x0, v0);
  v1 = fmaf(q2, x0, v1);
  v2 = fmaf(q3, x0, v2);
  w0 = fmaf(q0, xa, w0);
  w1 = fmaf(q0, xb, w1);
  w2 = fmaf(q0, xc, w2);
}

// ---- fused aggregation + MFMA post-transform ----
// Block = 1024 threads = 16 waves = 16 nodes (1 node/wave: block wall =
// max of 16 Poisson(16), beats 2-sequential-nodes/wave — r10 lesson).
// Phase 1: 8-deep gather batches (16 waves x 8 x 8 lines = 2x in-flight
// lines vs 4-deep; gather engine was line-limited at 2.0 TB/s vs 3.4
// demonstrated). Phase 2: wave w computes MFMA piece (j=w&3, part=w>>2).
// v_mfma_f32_16x16x16f16: A row=l&15, k=(l>>4)*4+i; B col=l&15; D col=l&15,
// row=(l>>4)*4+r (validated rounds 6-9).
__global__ __launch_bounds__(1024, 1) void k_aggpost(
    const int* __restrict__ cur, const uint4* __restrict__ ell,
    const unsigned short* __restrict__ Xp, const float* __restrict__ W00,
    const float* __restrict__ W11, const float* __restrict__ W01,
    const float* __restrict__ W10, float* __restrict__ out) {
  __shared__ unsigned short Pl[16 * PSTR];  // 16.5 KB
  int w = threadIdx.x >> 6;
  int o = threadIdx.x & 63;
  int nb = blockIdx.x * 16;
  int n = nb + w;

  // ---- phase 1: aggregate ----
  int d = cur[n];
  if (d > MAXD) d = MAXD;
  const uint4* base = ell + (size_t)n * MAXD;

  float u0 = 0.f, u1 = 0.f, v0 = 0.f, v1 = 0.f, v2 = 0.f;
  float w0 = 0.f, w1 = 0.f, w2 = 0.f;
  int i = 0;
  for (; i + 8 <= d; i += 8) {
    uint4 rec[8];
    ushort4v y[8];
#pragma unroll
    for (int q = 0; q < 8; q++) rec[q] = base[i + q];
#pragma unroll
    for (int q = 0; q < 8; q++)
      y[q] = *(const ushort4v*)(Xp + ((size_t)rec[q].x << 8) + (o << 2));
#pragma unroll
    for (int q = 0; q < 8; q++)
      eop(rec[q].y, rec[q].z, y[q], u0, u1, v0, v1, v2, w0, w1, w2);
  }
  for (; i + 4 <= d; i += 4) {
    uint4 rec[4];
    ushort4v y[4];
#pragma unroll
    for (int q = 0; q < 4; q++) rec[q] = base[i + q];
#pragma unroll
    for (int q = 0; q < 4; q++)
      y[q] = *(const ushort4v*)(Xp + ((size_t)rec[q].x << 8) + (o << 2));
#pragma unroll
    for (int q = 0; q < 4; q++)
      eop(rec[q].y, rec[q].z, y[q], u0, u1, v0, v1, v2, w0, w1, w2);
  }
  for (; i + 2 <= d; i += 2) {
    uint4 rec[2];
    ushort4v y[2];
#pragma unroll
    for (int q = 0; q < 2; q++) rec[q] = base[i + q];
#pragma unroll
    for (int q = 0; q < 2; q++)
      y[q] = *(const ushort4v*)(Xp + ((size_t)rec[q].x << 8) + (o << 2));
#pragma unroll
    for (int q = 0; q < 2; q++)
      eop(rec[q].y, rec[q].z, y[q], u0, u1, v0, v1, v2, w0, w1, w2);
  }
  if (i < d) {
    uint4 rec = base[i];
    ushort4v y = *(const ushort4v*)(Xp + ((size_t)rec.x << 8) + (o << 2));
    eop(rec.y, rec.z, y, u0, u1, v0, v1, v2, w0, w1, w2);
  }

  int rb = w * PSTR;
  Pl[rb + 0 * 64 + o] = f2h_bits(u0);
  Pl[rb + 1 * 64 + o] = f2h_bits(u1 * INV3);
  Pl[rb + 2 * 64 + o] = f2h_bits(v0);
  Pl[rb + 3 * 64 + o] = f2h_bits(v1);
  Pl[rb + 4 * 64 + o] = f2h_bits(v2);
  Pl[rb + 5 * 64 + o] = f2h_bits(w0);
  Pl[rb + 6 * 64 + o] = f2h_bits(w1);
  Pl[rb + 7 * 64 + o] = f2h_bits(w2);
  __syncthreads();

  // ---- phase 2: MFMA post-transform ----
  int j = w & 3;        // 16-col block
  int part = w >> 2;    // 0: out0; 1..3: out1_m
  int lr = o & 15, lq = o >> 4;
  int col = 16 * j + lr;

  int c0 = (part == 0) ? 0 : 2 + (part - 1);
  int c1 = (part == 0) ? 1 : 5 + (part - 1);
  const float* Wp0 = (part == 0) ? W00 : W01;
  const float* Wp1 = (part == 0) ? W11 : W10;

  f16x4 a0[4], a1[4], b0[4], b1[4];
#pragma unroll
  for (int kq = 0; kq < 4; kq++) {
    int od = kq * 16 + lq * 4;
    ushort4v t0 = *(const ushort4v*)(Pl + lr * PSTR + c0 * 64 + od);
    ushort4v t1 = *(const ushort4v*)(Pl + lr * PSTR + c1 * 64 + od);
    __builtin_memcpy(&a0[kq], &t0, 8);
    __builtin_memcpy(&a1[kq], &t1, 8);
#pragma unroll
    for (int ii = 0; ii < 4; ii++) {
      int row = od + ii;
      b0[kq][ii] = (_Float16)Wp0[row * 64 + col];
      b1[kq][ii] = (_Float16)Wp1[row * 64 + col];
    }
  }

  f32x4 acc = {0.f, 0.f, 0.f, 0.f};
#pragma unroll
  for (int kq = 0; kq < 4; kq++) {
    acc = __builtin_amdgcn_mfma_f32_16x16x16f16(a0[kq], b0[kq], acc, 0, 0, 0);
    acc = __builtin_amdgcn_mfma_f32_16x16x16f16(a1[kq], b1[kq], acc, 0, 0, 0);
  }

  if (part == 0) {
#pragma unroll
    for (int r = 0; r < 4; r++)
      out[(size_t)(nb + lq * 4 + r) * 256 + col] = acc[r];
  } else {
    int m = part - 1;
#pragma unroll
    for (int r = 0; r < 4; r++)
      out[(size_t)(nb + lq * 4 + r) * 256 + 64 + 3 * col + m] = acc[r];
  }
}

extern "C" void kernel_launch(void* const* d_in, const int* in_sizes, int n_in,
                              void* d_out, int out_size, void* d_ws,
                              size_t ws_size, hipStream_t stream) {
  const float* node_in = (const float*)d_in[0];
  const float* edge_attr = (const float*)d_in[1];
  const float* emb = (const float*)d_in[2];
  const float* w00 = (const float*)d_in[3];
  const float* w11 = (const float*)d_in[4];
  const float* w01 = (const float*)d_in[5];
  const float* w10 = (const float*)d_in[6];
  const float* fw1 = (const float*)d_in[7];
  const float* fw2 = (const float*)d_in[8];
  const int* esrc = (const int*)d_in[9];
  const int* edst = (const int*)d_in[10];
  float* out = (float*)d_out;

  char* ws = (char*)d_ws;
  unsigned short* Xp = (unsigned short*)ws; ws += (size_t)NN * 256 * 2;    // 25.6 MB
  uint4* ell = (uint4*)ws;                  ws += (size_t)NN * MAXD * 16;  // 51.2 MB
  int* cur = (int*)ws;                      ws += (size_t)NN * 4;          // 0.2 MB

  (void)hipMemsetAsync(cur, 0, (size_t)NN * 4, stream);
  k_combo<<<FILL_BLK + XC_BLK, 256, 0, stream>>>(
      node_in, Xp, edge_attr, emb, fw1, fw2, esrc, edst, cur, ell);
  k_aggpost<<<NN / 16, 1024, 0, stream>>>(cur, ell, Xp, w00, w11, w01, w10,
                                          out);
}

// Round 12
// 156.477 us; speedup vs baseline: 1.0528x; 1.0528x over previous
//
#include <hip/hip_runtime.h>

#define NE 800000
#define NN 50000
#define MAXD 64
#define FILL_BLK (NE / 256)   // 3125 edge-MLP blocks (exact)
#define XC_BLK (NN / 8)       // 6250 repack blocks (exact)
#define PSTR 516              // LDS P row stride in f16 (pad 4 -> conflict-free)

typedef __attribute__((ext_vector_type(4))) unsigned short ushort4v;
typedef __attribute__((ext_vector_type(8))) unsigned short ushort8;
typedef __attribute__((ext_vector_type(4))) _Float16 f16x4;
typedef __attribute__((ext_vector_type(4))) float f32x4;

static constexpr float ALPHA      = 0.08838834764831845f;   // 1/sqrt(128)
static constexpr float INV3       = 0.57735026918962576f;   // 1/sqrt(3)
static constexpr float INV_SQRT10 = 0.31622776601683794f;
static constexpr float SILU_NORM  = 1.679177f;
static constexpr float QSCALE     = ALPHA * 0.25f;          // fold 1/sqrt(16)

__device__ __forceinline__ unsigned short f2h_bits(float f) {
  _Float16 h = (_Float16)f;
  unsigned short b;
  __builtin_memcpy(&b, &h, 2);
  return b;
}
__device__ __forceinline__ float h2f_bits(unsigned int b) {
  unsigned short s = (unsigned short)b;
  _Float16 h;
  __builtin_memcpy(&h, &s, 2);
  return (float)h;
}
__device__ __forceinline__ unsigned int packh2(float lo, float hi) {
  return (unsigned int)f2h_bits(lo) | ((unsigned int)f2h_bits(hi) << 16);
}

// ---- fused: edge MLP -> ELL fill (blocks [0, FILL_BLK)) and
//      X f32 -> f16 repack (blocks [FILL_BLK, FILL_BLK+XC_BLK)).
__global__ __launch_bounds__(256) void k_combo(
    const float* __restrict__ X, unsigned short* __restrict__ Xp,
    const float* __restrict__ attr, const float* __restrict__ emb,
    const float* __restrict__ w1, const float* __restrict__ w2,
    const int* __restrict__ esrc, const int* __restrict__ edst,
    int* __restrict__ cur, uint4* __restrict__ ell) {
  __shared__ float lds[2816];  // 11.3 KB, shared by both paths
  if (blockIdx.x < FILL_BLK) {
    // ---- edge MLP + ELL fill; atomic issued EARLY, hidden under MLP ----
    int eb = blockIdx.x * 256;
    int e = eb + threadIdx.x;
    int dst = edst[e];
    int src = esrc[e];
    float4 a = *(const float4*)(attr + (size_t)e * 4);
    int slot = atomicAdd(&cur[dst], 1);

    const float* ebase = emb + (size_t)eb * 10;
#pragma unroll
    for (int j = 0; j < 10; j++)
      lds[j * 256 + threadIdx.x] = ebase[j * 256 + threadIdx.x];
    __syncthreads();
    const float* x = lds + threadIdx.x * 10;
    float r = 0.f;
#pragma unroll
    for (int j = 0; j < 64; j++) {
      float d = 0.f;
#pragma unroll
      for (int k = 0; k < 10; k++) d = fmaf(x[k], w1[k * 64 + j], d);
      d *= INV_SQRT10;
      float h = d * __builtin_amdgcn_rcpf(1.f + __expf(-d)) * SILU_NORM;
      r = fmaf(h, w2[j], r);
    }
    r *= 0.125f * QSCALE;  // fold 1/sqrt(64), alpha, 1/sqrt(16)
    if (slot < MAXD) {
      // single 16B scattered store per edge (one cache line touched)
      ell[(size_t)dst * MAXD + slot] =
          make_uint4((unsigned)src, packh2(r * a.x, r * a.y),
                     packh2(r * a.z, r * a.w), 0u);
    }
  } else {
    // ---- X -> Xp repack: 8 node rows staged via coalesced float4 loads ----
    int n0 = (blockIdx.x - FILL_BLK) * 8;
    const float4* Xs = (const float4*)(X + (size_t)n0 * 256);
    float4* L4 = (float4*)lds;
    L4[threadIdx.x] = Xs[threadIdx.x];
    L4[256 + threadIdx.x] = Xs[256 + threadIdx.x];
    __syncthreads();
    int o = threadIdx.x & 63;
    int nl = threadIdx.x >> 6;
#pragma unroll
    for (int ii = 0; ii < 2; ii++) {
      int n_l = nl + ii * 4;
      const float* row = lds + n_l * 256;
      ushort4v v;
      v[0] = f2h_bits(row[o]);
      v[1] = f2h_bits(row[64 + 3 * o]);
      v[2] = f2h_bits(row[64 + 3 * o + 1]);
      v[3] = f2h_bits(row[64 + 3 * o + 2]);
      *(ushort4v*)(Xp + (size_t)(n0 + n_l) * 256 + o * 4) = v;
    }
  }
}

// ---- raw-feature accumulate: one lane, TWO o-features of one edge ----
__device__ __forceinline__ void eop2(unsigned int q01, unsigned int q23,
                                     ushort8 y, float& u0a, float& u1a,
                                     float& v0a, float& v1a, float& v2a,
                                     float& w0a, float& w1a, float& w2a,
                                     float& u0b, float& u1b, float& v0b,
                                     float& v1b, float& v2b, float& w0b,
                                     float& w1b, float& w2b) {
  float q0 = h2f_bits(q01), q1 = h2f_bits(q01 >> 16);
  float q2 = h2f_bits(q23), q3 = h2f_bits(q23 >> 16);
  float x0 = h2f_bits(y[0]), xa = h2f_bits(y[1]);
  float xb = h2f_bits(y[2]), xc = h2f_bits(y[3]);
  u0a = fmaf(q0, x0, u0a);
  u1a = fmaf(q1, xa, u1a);
  u1a = fmaf(q2, xb, u1a);
  u1a = fmaf(q3, xc, u1a);
  v0a = fmaf(q1, x0, v0a);
  v1a = fmaf(q2, x0, v1a);
  v2a = fmaf(q3, x0, v2a);
  w0a = fmaf(q0, xa, w0a);
  w1a = fmaf(q0, xb, w1a);
  w2a = fmaf(q0, xc, w2a);
  float z0 = h2f_bits(y[4]), za = h2f_bits(y[5]);
  float zb = h2f_bits(y[6]), zc = h2f_bits(y[7]);
  u0b = fmaf(q0, z0, u0b);
  u1b = fmaf(q1, za, u1b);
  u1b = fmaf(q2, zb, u1b);
  u1b = fmaf(q3, zc, u1b);
  v0b = fmaf(q1, z0, v0b);
  v1b = fmaf(q2, z0, v1b);
  v2b = fmaf(q3, z0, v2b);
  w0b = fmaf(q0, za, w0b);
  w1b = fmaf(q0, zb, w1b);
  w2b = fmaf(q0, zc, w2b);
}

// ---- fused aggregation + MFMA post-transform ----
// Block = 1024 threads = 16 waves = 16 nodes (r9 shape). Phase 1 processes
// TWO edges per wave-instruction: lanes 0-31 = even-slot edge, lanes 32-63 =
// odd-slot edge; each lane covers o-features {2*lp, 2*lp+1} (16B gather =
// 2 Xp lines per instruction -> 2x lines in flight, half the loop trips).
// End-of-loop __shfl_xor(32) merges the two half-wave partial sums.
// Phase 2: wave w computes MFMA piece (j=w&3, part=w>>2); layouts validated
// rounds 6-9.
__global__ __launch_bounds__(1024, 2) void k_aggpost(
    const int* __restrict__ cur, const uint4* __restrict__ ell,
    const unsigned short* __restrict__ Xp, const float* __restrict__ W00,
    const float* __restrict__ W11, const float* __restrict__ W01,
    const float* __restrict__ W10, float* __restrict__ out) {
  __shared__ unsigned short Pl[16 * PSTR];  // 16.5 KB
  int w = threadIdx.x >> 6;
  int l = threadIdx.x & 63;
  int half = l >> 5;
  int lp = l & 31;
  int nb = blockIdx.x * 16;
  int n = nb + w;

  // ---- phase 1: aggregate (2 edges per instruction) ----
  int d = cur[n];
  if (d > MAXD) d = MAXD;
  const uint4* base = ell + (size_t)n * MAXD;

  float u0a = 0.f, u1a = 0.f, v0a = 0.f, v1a = 0.f, v2a = 0.f;
  float w0a = 0.f, w1a = 0.f, w2a = 0.f;
  float u0b = 0.f, u1b = 0.f, v0b = 0.f, v1b = 0.f, v2b = 0.f;
  float w0b = 0.f, w1b = 0.f, w2b = 0.f;

  int np = (d + 1) >> 1;  // pairs
  int i = 0;
  for (; i + 4 <= np; i += 4) {
    uint4 rec[4];
    ushort8 y[4];
#pragma unroll
    for (int q = 0; q < 4; q++) {
      int idx = 2 * (i + q) + half;
      int cidx = idx < d ? idx : d - 1;  // d>=1 inside loop
      rec[q] = base[cidx];
      if (idx >= d) {
        rec[q].y = 0u;
        rec[q].z = 0u;
      }
    }
#pragma unroll
    for (int q = 0; q < 4; q++)
      y[q] = *(const ushort8*)(Xp + ((size_t)rec[q].x << 8) + (lp << 3));
#pragma unroll
    for (int q = 0; q < 4; q++)
      eop2(rec[q].y, rec[q].z, y[q], u0a, u1a, v0a, v1a, v2a, w0a, w1a, w2a,
           u0b, u1b, v0b, v1b, v2b, w0b, w1b, w2b);
  }
  for (; i < np; i++) {
    int idx = 2 * i + half;
    int cidx = idx < d ? idx : d - 1;
    uint4 rec = base[cidx];
    if (idx >= d) {
      rec.y = 0u;
      rec.z = 0u;
    }
    ushort8 y = *(const ushort8*)(Xp + ((size_t)rec.x << 8) + (lp << 3));
    eop2(rec.y, rec.z, y, u0a, u1a, v0a, v1a, v2a, w0a, w1a, w2a, u0b, u1b,
         v0b, v1b, v2b, w0b, w1b, w2b);
  }

  // merge half-wave partials (lane l <-> l^32 worked the same o-pair)
  u0a += __shfl_xor(u0a, 32, 64);
  u1a += __shfl_xor(u1a, 32, 64);
  v0a += __shfl_xor(v0a, 32, 64);
  v1a += __shfl_xor(v1a, 32, 64);
  v2a += __shfl_xor(v2a, 32, 64);
  w0a += __shfl_xor(w0a, 32, 64);
  w1a += __shfl_xor(w1a, 32, 64);
  w2a += __shfl_xor(w2a, 32, 64);
  u0b += __shfl_xor(u0b, 32, 64);
  u1b += __shfl_xor(u1b, 32, 64);
  v0b += __shfl_xor(v0b, 32, 64);
  v1b += __shfl_xor(v1b, 32, 64);
  v2b += __shfl_xor(v2b, 32, 64);
  w0b += __shfl_xor(w0b, 32, 64);
  w1b += __shfl_xor(w1b, 32, 64);
  w2b += __shfl_xor(w2b, 32, 64);

  int rb = w * PSTR;
  int om = 2 * lp + half;  // lanes<32 write even o, lanes>=32 odd o
  Pl[rb + 0 * 64 + om] = f2h_bits(half ? u0b : u0a);
  Pl[rb + 1 * 64 + om] = f2h_bits((half ? u1b : u1a) * INV3);
  Pl[rb + 2 * 64 + om] = f2h_bits(half ? v0b : v0a);
  Pl[rb + 3 * 64 + om] = f2h_bits(half ? v1b : v1a);
  Pl[rb + 4 * 64 + om] = f2h_bits(half ? v2b : v2a);
  Pl[rb + 5 * 64 + om] = f2h_bits(half ? w0b : w0a);
  Pl[rb + 6 * 64 + om] = f2h_bits(half ? w1b : w1a);
  Pl[rb + 7 * 64 + om] = f2h_bits(half ? w2b : w2a);
  __syncthreads();

  // ---- phase 2: MFMA post-transform ----
  int j = w & 3;        // 16-col block
  int part = w >> 2;    // 0: out0; 1..3: out1_m
  int lr = l & 15, lq = l >> 4;
  int col = 16 * j + lr;

  int c0 = (part == 0) ? 0 : 2 + (part - 1);
  int c1 = (part == 0) ? 1 : 5 + (part - 1);
  const float* Wp0 = (part == 0) ? W00 : W01;
  const float* Wp1 = (part == 0) ? W11 : W10;

  f16x4 a0[4], a1[4], b0[4], b1[4];
#pragma unroll
  for (int kq = 0; kq < 4; kq++) {
    int od = kq * 16 + lq * 4;
    ushort4v t0 = *(const ushort4v*)(Pl + lr * PSTR + c0 * 64 + od);
    ushort4v t1 = *(const ushort4v*)(Pl + lr * PSTR + c1 * 64 + od);
    __builtin_memcpy(&a0[kq], &t0, 8);
    __builtin_memcpy(&a1[kq], &t1, 8);
#pragma unroll
    for (int ii = 0; ii < 4; ii++) {
      int row = od + ii;
      b0[kq][ii] = (_Float16)Wp0[row * 64 + col];
      b1[kq][ii] = (_Float16)Wp1[row * 64 + col];
    }
  }

  f32x4 acc = {0.f, 0.f, 0.f, 0.f};
#pragma unroll
  for (int kq = 0; kq < 4; kq++) {
    acc = __builtin_amdgcn_mfma_f32_16x16x16f16(a0[kq], b0[kq], acc, 0, 0, 0);
    acc = __builtin_amdgcn_mfma_f32_16x16x16f16(a1[kq], b1[kq], acc, 0, 0, 0);
  }

  if (part == 0) {
#pragma unroll
    for (int r = 0; r < 4; r++)
      out[(size_t)(nb + lq * 4 + r) * 256 + col] = acc[r];
  } else {
    int m = part - 1;
#pragma unroll
    for (int r = 0; r < 4; r++)
      out[(size_t)(nb + lq * 4 + r) * 256 + 64 + 3 * col + m] = acc[r];
  }
}

extern "C" void kernel_launch(void* const* d_in, const int* in_sizes, int n_in,
                              void* d_out, int out_size, void* d_ws,
                              size_t ws_size, hipStream_t stream) {
  const float* node_in = (const float*)d_in[0];
  const float* edge_attr = (const float*)d_in[1];
  const float* emb = (const float*)d_in[2];
  const float* w00 = (const float*)d_in[3];
  const float* w11 = (const float*)d_in[4];
  const float* w01 = (const float*)d_in[5];
  const float* w10 = (const float*)d_in[6];
  const float* fw1 = (const float*)d_in[7];
  const float* fw2 = (const float*)d_in[8];
  const int* esrc = (const int*)d_in[9];
  const int* edst = (const int*)d_in[10];
  float* out = (float*)d_out;

  char* ws = (char*)d_ws;
  unsigned short* Xp = (unsigned short*)ws; ws += (size_t)NN * 256 * 2;    // 25.6 MB
  uint4* ell = (uint4*)ws;                  ws += (size_t)NN * MAXD * 16;  // 51.2 MB
  int* cur = (int*)ws;                      ws += (size_t)NN * 4;          // 0.2 MB

  (void)hipMemsetAsync(cur, 0, (size_t)NN * 4, stream);
  k_combo<<<FILL_BLK + XC_BLK, 256, 0, stream>>>(
      node_in, Xp, edge_attr, emb, fw1, fw2, esrc, edst, cur, ell);
  k_aggpost<<<NN / 16, 1024, 0, stream>>>(cur, ell, Xp, w00, w11, w01, w10,
                                          out);
}